// Round 17
// baseline (222.704 us; speedup 1.0000x reference)
//
#include <hip/hip_runtime.h>
#include <stdint.h>

// ---------------- ws layout ----------------
// floats: [0..63] future_load | [64..127] P sums | [128..191] cnt | [192] comp
// ints  : (ws+200): [0] qcount, [8..] queue entries
// bytes : +80000  : W frag-major image, 128 chunks x 16384 B.
// floats: +550000 : zx0[50][256] — layer-0 LSTM x-part, precomputed by prep block 128
// floats: +680000 : logits [16384][128] (atomic-accumulated, zeroed by prep)
#define IMG_OFF_BYTES 80000
#define CHUNK_IMG 16384
#define ZX0_OFF 550000
#define LOGITS_OFF 680000
#define TAU 1e-3f

#define XLOFF 5120          // x_lo offset within an x buffer
#define BUF_STRIDE 10240    // x buffer: 64 rows x 80 B (hi) + same (lo)

typedef __attribute__((ext_vector_type(8))) short short8v;
typedef __attribute__((ext_vector_type(4))) short short4v;
typedef __attribute__((ext_vector_type(4))) float f32x4;

__device__ __forceinline__ float rlf(float v, int l) {
  return __int_as_float(__builtin_amdgcn_readlane(__float_as_int(v), l));
}
__device__ __forceinline__ float wsum(float v) {
#pragma unroll
  for (int o = 32; o; o >>= 1) v += __shfl_xor(v, o, 64);
  return v;
}
__device__ __forceinline__ float wmax(float v) {
#pragma unroll
  for (int o = 32; o; o >>= 1) v = fmaxf(v, __shfl_xor(v, o, 64));
  return v;
}
__device__ __forceinline__ unsigned short f2bf(float f) {
  unsigned u = __float_as_uint(f);
  u += 0x7fffu + ((u >> 16) & 1u);
  return (unsigned short)(u >> 16);
}
__device__ __forceinline__ float bf2f(unsigned short h) {
  return __uint_as_float(((unsigned)h) << 16);
}
__device__ __forceinline__ short8v frag8(const char* p0, const char* p1) {
  short4v a = *(const short4v*)p0;
  short4v b = *(const short4v*)p1;
  return __builtin_shufflevector(a, b, 0, 1, 2, 3, 4, 5, 6, 7);
}

// LDS-only barrier (R9/R10-verified): orders ds traffic across waves WITHOUT
// draining vmcnt — global loads stay in flight across the barrier.
__device__ __forceinline__ void lds_barrier() {
  asm volatile("s_waitcnt lgkmcnt(0)" ::: "memory");
  __builtin_amdgcn_s_barrier();
  asm volatile("" ::: "memory");
  __builtin_amdgcn_sched_barrier(0);
}

// ---------------- K0: prep — zero accums+logits, W image, zx0 precompute ------
__global__ __launch_bounds__(256) void prep_kernel(
    const float* __restrict__ gate_w, const float* __restrict__ cp_w1,
    const float* __restrict__ lb, const float* __restrict__ wih0,
    float* __restrict__ ws)
{
  const int c = blockIdx.x;
  const int tid = threadIdx.x;
  __shared__ float slb[3200];
  if (c == 128) {
    for (int i = tid; i < 3200; i += 256) slb[i] = lb[i];
    float wiR[64];
#pragma unroll
    for (int j = 0; j < 64; j += 4)
      *(float4*)&wiR[j] = *(const float4*)(wih0 + tid * 64 + j);
    __syncthreads();
    float* zx0 = ws + ZX0_OFF;
#pragma unroll 1
    for (int t = 0; t < 50; ++t) {
      const float* xt = slb + t * 64;
      float a0 = 0.f, a1 = 0.f, a2 = 0.f, a3 = 0.f;
#pragma unroll
      for (int j = 0; j < 64; j += 4) {
        a0 = fmaf(xt[j + 0], wiR[j + 0], a0);
        a1 = fmaf(xt[j + 1], wiR[j + 1], a1);
        a2 = fmaf(xt[j + 2], wiR[j + 2], a2);
        a3 = fmaf(xt[j + 3], wiR[j + 3], a3);
      }
      zx0[t * 256 + tid] = (a0 + a1) + (a2 + a3);
    }
    return;
  }
  if (c == 0 && tid < 144) ws[64 + tid] = 0.f;  // P, cnt, comp, queue header
  {  // zero this block's logits slab (16384 floats)
    float4 z = make_float4(0.f, 0.f, 0.f, 0.f);
    float4* lz = (float4*)(ws + LOGITS_OFF + c * 16384);
#pragma unroll
    for (int i = 0; i < 16; ++i) lz[tid + i * 256] = z;
  }
  const int row = tid >> 1;       // W row (output col) 0..127
  const int half = tid & 1;       // k half: 0 -> k0..15, 1 -> k16..31
  const float* src = ((row < 64) ? (gate_w + (size_t)row * 4096)
                                 : (cp_w1 + (size_t)(row - 64) * 4096)) + c * 32 + half * 16;
  float v[16];
#pragma unroll
  for (int j = 0; j < 4; ++j) *(float4*)&v[j * 4] = *(const float4*)(src + j * 4);
  const int g = row >> 4, r15 = row & 15;
  char* img = (char*)ws + IMG_OFF_BYTES + (size_t)c * CHUNK_IMG + g * 2048;
#pragma unroll
  for (int q = 0; q < 4; ++q) {
    unsigned short h0 = f2bf(v[4 * q + 0]), h1 = f2bf(v[4 * q + 1]);
    unsigned short h2 = f2bf(v[4 * q + 2]), h3 = f2bf(v[4 * q + 3]);
    unsigned short l0 = f2bf(v[4 * q + 0] - bf2f(h0));
    unsigned short l1 = f2bf(v[4 * q + 1] - bf2f(h1));
    unsigned short l2 = f2bf(v[4 * q + 2] - bf2f(h2));
    unsigned short l3 = f2bf(v[4 * q + 3] - bf2f(h3));
    uint2 hv, lv;
    hv.x = (unsigned)h0 | ((unsigned)h1 << 16);
    hv.y = (unsigned)h2 | ((unsigned)h3 << 16);
    lv.x = (unsigned)l0 | ((unsigned)l1 << 16);
    lv.y = (unsigned)l2 | ((unsigned)l3 << 16);
    const int l = q * 16 + r15;
    *(uint2*)(img + l * 16 + half * 8) = hv;            // hi KB
    *(uint2*)(img + 1024 + l * 16 + half * 8) = lv;     // lo KB
  }
}

// ---------------- LSTM (device fn, block 0 of gemm kernel) --------------------
// R16-verified: layer 0 whR-only (unspilled at ~92-96 budget); layer 1 resident
// wiR+whR (regalloc anchor, spills but only one layer).
__device__ void lstm_device(
    char* ldsbase,
    const float* __restrict__ wih1, const float* __restrict__ whh0,
    const float* __restrict__ bih0, const float* __restrict__ bhh0,
    const float* __restrict__ whh1,
    const float* __restrict__ bih1, const float* __restrict__ bhh1,
    const float* __restrict__ head_w, const float* __restrict__ head_b,
    float* __restrict__ ws, float* __restrict__ out, int N)
{
  float* h1s  = (float*)ldsbase;            // 3200
  float* zbuf = h1s + 3200;                 // 256
  float* hbuf = zbuf + 256;                 // 64
  float* preds = hbuf + 64;                 // 640
  const int tid = threadIdx.x;
  const int lane = tid & 63;
  const float* zx0 = ws + ZX0_OFF;

  float hv = 0.f;
  // ---------- layer 0: whR-only sequential loop ----------
  {
    float whR[64];
#pragma unroll
    for (int j = 0; j < 64; j += 4)
      *(float4*)&whR[j] = *(const float4*)(whh0 + tid * 64 + j);
    const float bsum = bih0[tid] + bhh0[tid];
    float c_reg = 0.f;
    hv = 0.f;
    if (tid < 64) hbuf[tid] = 0.f;
    __syncthreads();
    float zcur = zx0[tid];
#pragma unroll 1
    for (int t = 0; t < 50; ++t) {
      float znxt = 0.f;
      if (t < 49) znxt = zx0[(t + 1) * 256 + tid];
      float a0 = bsum + zcur, a1 = 0.f, a2 = 0.f, a3 = 0.f;
#pragma unroll
      for (int j = 0; j < 64; j += 4) {
        a0 = fmaf(rlf(hv, j + 0), whR[j + 0], a0);
        a1 = fmaf(rlf(hv, j + 1), whR[j + 1], a1);
        a2 = fmaf(rlf(hv, j + 2), whR[j + 2], a2);
        a3 = fmaf(rlf(hv, j + 3), whR[j + 3], a3);
      }
      zbuf[tid] = (a0 + a1) + (a2 + a3);
      __syncthreads();
      if (tid < 64) {
        const float zi = zbuf[tid], zf = zbuf[64 + tid];
        const float zg = zbuf[128 + tid], zo = zbuf[192 + tid];
        const float si = 1.f / (1.f + expf(-zi));
        const float sf = 1.f / (1.f + expf(-zf));
        const float so = 1.f / (1.f + expf(-zo));
        c_reg = sf * c_reg + si * tanhf(zg);
        const float h = so * tanhf(c_reg);
        hbuf[tid] = h;
        h1s[t * 64 + tid] = h;
      }
      __syncthreads();
      hv = hbuf[lane];
      zcur = znxt;
    }
    __syncthreads();
  }
  // ---------- layer 1: resident wiR+whR (anchor) ----------
  {
    float wiR[64], whR[64];
#pragma unroll
    for (int j = 0; j < 64; j += 4) {
      *(float4*)&wiR[j] = *(const float4*)(wih1 + tid * 64 + j);
      *(float4*)&whR[j] = *(const float4*)(whh1 + tid * 64 + j);
    }
    const float bsum = bih1[tid] + bhh1[tid];
    float c_reg = 0.f;
    hv = 0.f;
    if (tid < 64) hbuf[tid] = 0.f;
    __syncthreads();
#pragma unroll 1
    for (int t = 0; t < 50; ++t) {
      const float xv = h1s[t * 64 + lane];
      float a0 = bsum, a1 = 0.f, a2 = 0.f, a3 = 0.f;
#pragma unroll
      for (int j = 0; j < 64; j += 4) {
        a0 = fmaf(rlf(xv, j + 0), wiR[j + 0], a0);
        a1 = fmaf(rlf(xv, j + 1), wiR[j + 1], a1);
        a2 = fmaf(rlf(xv, j + 2), wiR[j + 2], a2);
        a3 = fmaf(rlf(xv, j + 3), wiR[j + 3], a3);
      }
#pragma unroll
      for (int j = 0; j < 64; j += 4) {
        a0 = fmaf(rlf(hv, j + 0), whR[j + 0], a0);
        a1 = fmaf(rlf(hv, j + 1), whR[j + 1], a1);
        a2 = fmaf(rlf(hv, j + 2), whR[j + 2], a2);
        a3 = fmaf(rlf(hv, j + 3), whR[j + 3], a3);
      }
      zbuf[tid] = (a0 + a1) + (a2 + a3);
      __syncthreads();
      if (tid < 64) {
        const float zi = zbuf[tid], zf = zbuf[64 + tid];
        const float zg = zbuf[128 + tid], zo = zbuf[192 + tid];
        const float si = 1.f / (1.f + expf(-zi));
        const float sf = 1.f / (1.f + expf(-zf));
        const float so = 1.f / (1.f + expf(-zo));
        c_reg = sf * c_reg + si * tanhf(zg);
        const float h = so * tanhf(c_reg);
        hbuf[tid] = h;
      }
      __syncthreads();
      hv = hbuf[lane];
    }
    __syncthreads();
  }
  // head
  for (int o = tid; o < 640; o += 256) {
    const float* hw = head_w + o * 64;
    float a0 = 0.f, a1 = 0.f, a2 = 0.f, a3 = 0.f;
#pragma unroll
    for (int j = 0; j < 64; j += 4) {
      a0 = fmaf(rlf(hv, j + 0), hw[j + 0], a0);
      a1 = fmaf(rlf(hv, j + 1), hw[j + 1], a1);
      a2 = fmaf(rlf(hv, j + 2), hw[j + 2], a2);
      a3 = fmaf(rlf(hv, j + 3), hw[j + 3], a3);
    }
    preds[o] = (a0 + a1) + (a2 + a3) + head_b[o];
  }
  __syncthreads();
  if (tid < 64) {
    float m = 0.f;
#pragma unroll
    for (int h = 0; h < 10; ++h) m += preds[tid * 10 + h];
    m = m / 10.f;
    const float mx = wmax(m);
    const float p = expf(m - mx);
    const float s = wsum(p);
    const float flv = p / s;
    ws[tid] = flv;
    out[4 * N + 2 + tid] = flv;
  }
}

// ---------------- K2: split-K(x4) bf16-split MFMA GEMM ------------------------
// K-loop = R9-verified schedule: lds_barrier (no vmcnt drain) + W ping-pong
// prefetch (whA/whB one chunk ahead). Retested UNMASKED now that the LSTM block
// (~110us) no longer sets the merged dispatch duration.
__global__ __launch_bounds__(256, 1) void gemm_kernel(
    const float* __restrict__ x, float* __restrict__ ws, float* __restrict__ out,
    const float* __restrict__ wih1, const float* __restrict__ whh0,
    const float* __restrict__ bih0, const float* __restrict__ bhh0,
    const float* __restrict__ whh1,
    const float* __restrict__ bih1, const float* __restrict__ bhh1,
    const float* __restrict__ head_w, const float* __restrict__ head_b,
    int N)
{
  __shared__ __align__(16) char lds[30720];
  if (blockIdx.x == 0) {
    lstm_device(lds, wih1, whh0, bih0, bhh0, whh1, bih1, bhh1,
                head_w, head_b, ws, out, N);
    return;
  }
  const int b = blockIdx.x - 1;       // 0..1023
  const int tb = (b & 255) * 64;      // token tile
  const int ck0 = (b >> 8) * 32;      // K-quarter start chunk
  const int tid = threadIdx.x;
  const int lane = tid & 63;
  const int wv = __builtin_amdgcn_readfirstlane(tid >> 6);  // 0..3
  const int r15 = lane & 15;
  const int fo = (lane >> 4) * 8;     // frag byte offset within 64B row
  const int row = tid >> 2;           // x staging row 0..63
  const int kslot = tid & 3;          // 8-float group
  const float* xsrc = x + (size_t)(tb + row) * 4096 + kslot * 8;
  const char* wimg = (const char*)ws + IMG_OFF_BYTES;
  char* buf0 = lds;
  char* buf1 = lds + BUF_STRIDE;

  f32x4 acc[4][2];
#pragma unroll
  for (int mi = 0; mi < 4; ++mi)
#pragma unroll
    for (int ni = 0; ni < 2; ++ni) acc[mi][ni] = (f32x4)0.f;

  float xa[8], xb[8];
  short8v whA[2], wlA[2], whB[2], wlB[2];

#define LOADX(R, C)                                                        \
  { *(float4*)&R[0] = *(const float4*)(xsrc + (size_t)(C) * 32);           \
    *(float4*)&R[4] = *(const float4*)(xsrc + (size_t)(C) * 32 + 4); }

#define WRITEX(R, BASE)                                                    \
  { uint4 hv, lv; unsigned hu[4], lu[4];                                   \
    _Pragma("unroll")                                                      \
    for (int i = 0; i < 4; ++i) {                                          \
      unsigned short h0 = f2bf(R[2 * i]), h1 = f2bf(R[2 * i + 1]);         \
      unsigned short l0 = f2bf(R[2 * i] - bf2f(h0));                       \
      unsigned short l1 = f2bf(R[2 * i + 1] - bf2f(h1));                   \
      hu[i] = (unsigned)h0 | ((unsigned)h1 << 16);                         \
      lu[i] = (unsigned)l0 | ((unsigned)l1 << 16);                         \
    }                                                                      \
    hv.x = hu[0]; hv.y = hu[1]; hv.z = hu[2]; hv.w = hu[3];                \
    lv.x = lu[0]; lv.y = lu[1]; lv.z = lu[2]; lv.w = lu[3];                \
    *(uint4*)((BASE) + row * 80 + kslot * 16) = hv;                        \
    *(uint4*)((BASE) + XLOFF + row * 80 + kslot * 16) = lv; }

#define WLOADR(C, WH, WL)                                                  \
  { const char* wb = wimg + (size_t)(C) * CHUNK_IMG + wv * 4096 + lane * 16; \
    WH[0] = *(const short8v*)wb;                                           \
    WL[0] = *(const short8v*)(wb + 1024);                                  \
    WH[1] = *(const short8v*)(wb + 2048);                                  \
    WL[1] = *(const short8v*)(wb + 3072); }

#define COMPUTE(BASE, WH, WL)                                              \
  { short8v xh[4], xl[4];                                                  \
    _Pragma("unroll")                                                      \
    for (int mi = 0; mi < 4; ++mi) {                                       \
      const char* p = (BASE) + (mi * 16 + r15) * 80 + fo;                  \
      xh[mi] = frag8(p, p + 32);                                           \
      xl[mi] = frag8(p + XLOFF, p + XLOFF + 32);                           \
    }                                                                      \
    _Pragma("unroll")                                                      \
    for (int mi = 0; mi < 4; ++mi)                                         \
      _Pragma("unroll")                                                    \
      for (int ni = 0; ni < 2; ++ni) {                                     \
        acc[mi][ni] = __builtin_amdgcn_mfma_f32_16x16x32_bf16(             \
            xh[mi], WH[ni], acc[mi][ni], 0, 0, 0);                         \
        acc[mi][ni] = __builtin_amdgcn_mfma_f32_16x16x32_bf16(             \
            xh[mi], WL[ni], acc[mi][ni], 0, 0, 0);                         \
        acc[mi][ni] = __builtin_amdgcn_mfma_f32_16x16x32_bf16(             \
            xl[mi], WH[ni], acc[mi][ni], 0, 0, 0);                         \
      } }

  // prologue
  LOADX(xa, ck0);
  LOADX(xb, ck0 + 1);
  WLOADR(ck0, whA, wlA);
  WRITEX(xa, buf0);
  lds_barrier();

#pragma unroll 1
  for (int cc = 0; cc < 16; ++cc) {
    const int c0 = ck0 + 2 * cc, c1 = c0 + 1;
    // even chunk: compute buf0 with whA; prefetch W(c1), x(c0+2)
    WLOADR(c1, whB, wlB);
    if (cc < 15) LOADX(xa, c0 + 2);
    COMPUTE(buf0, whA, wlA);
    WRITEX(xb, buf1);
    lds_barrier();
    // odd chunk: compute buf1 with whB; prefetch W(c0+2), x(c1+2)
    if (cc < 15) WLOADR(c0 + 2, whA, wlA);
    if (cc < 15) LOADX(xb, c1 + 2);
    COMPUTE(buf1, whB, wlB);
    if (cc < 15) WRITEX(xa, buf0);
    lds_barrier();
  }

  // atomic-accumulate partial logits (4 contributions/address; jitter ~1e-6 << TAU)
  float* lg = ws + LOGITS_OFF;
#pragma unroll
  for (int mi = 0; mi < 4; ++mi)
#pragma unroll
    for (int ni = 0; ni < 2; ++ni)
#pragma unroll
      for (int r = 0; r < 4; ++r) {
        const int tokrow = tb + mi * 16 + (lane >> 4) * 4 + r;
        const int col = wv * 32 + ni * 16 + r15;
        atomicAdd(&lg[(size_t)tokrow * 128 + col], acc[mi][ni][r]);
      }
#undef LOADX
#undef WRITEX
#undef WLOADR
#undef COMPUTE
}

// ---------------- K3: epilogue — softmax, top-2, margins->queue, partial sums --
__global__ __launch_bounds__(256) void epi_kernel(
    const float* __restrict__ eb_p, const float* __restrict__ cp_b1,
    const float* __restrict__ cp_w2, const float* __restrict__ cp_b2,
    float* __restrict__ ws, float* __restrict__ out, int N)
{
  const int tid = threadIdx.x;
  const int lane = tid & 63;
  const int wv = __builtin_amdgcn_readfirstlane(tid >> 6);
  const int tb = blockIdx.x * 32;
  const float* lg = ws + LOGITS_OFF;
  int* qd = (int*)(ws + 200);
  __shared__ float sP[64];
  __shared__ float scnt[64];
  __shared__ float scomp;
  if (tid < 64) { sP[tid] = 0.f; scnt[tid] = 0.f; }
  if (tid == 0) scomp = 0.f;
  __syncthreads();

  const float eb = eb_p[lane];
  const float fl = ws[lane];
  const float cb1 = cp_b1[lane];
  const float cw2 = cp_w2[lane];
  const float cb2 = cp_b2[0];
  float psum_local = 0.f, comp_local = 0.f;
  float* o_ts = out;
  float* o_ti = out + 2 * N;

#pragma unroll 1
  for (int tt = 0; tt < 8; ++tt) {
    const int tok = tb + wv * 8 + tt;
    const float lgv = lg[(size_t)tok * 128 + lane];
    const float lc  = lg[(size_t)tok * 128 + 64 + lane];
    float rr = fmaxf(lc + cb1, 0.f) * cw2;
    rr = wsum(rr);
    const float comp = 1.f / (1.f + expf(-(rr + cb2)));
    comp_local += comp;
    const float a = lgv + eb - fl;
    float m1 = a; int i1 = lane;
#pragma unroll
    for (int o = 32; o; o >>= 1) {
      const float ov = __shfl_xor(m1, o, 64);
      const int oi = __shfl_xor(i1, o, 64);
      if (ov > m1 || (ov == m1 && oi < i1)) { m1 = ov; i1 = oi; }
    }
    float m2 = (lane == i1) ? -1e30f : a; int i2 = lane;
#pragma unroll
    for (int o = 32; o; o >>= 1) {
      const float ov = __shfl_xor(m2, o, 64);
      const int oi = __shfl_xor(i2, o, 64);
      if (ov > m2 || (ov == m2 && oi < i2)) { m2 = ov; i2 = oi; }
    }
    float m3 = (lane == i1 || lane == i2) ? -1e30f : a;
#pragma unroll
    for (int o = 32; o; o >>= 1) m3 = fmaxf(m3, __shfl_xor(m3, o, 64));
    const float p = expf(a - m1);
    const float ssum = wsum(p);
    const float prob = p / ssum;
    psum_local += prob;
    const float s1 = rlf(prob, i1);
    const float s2 = rlf(prob, i2);
    if (lane == 0) {
      const float inv = 1.f / (s1 + s2);
      o_ts[tok * 2 + 0] = s1 * inv;
      o_ts[tok * 2 + 1] = s2 * inv;
      o_ti[tok * 2 + 0] = (float)i1;
      o_ti[tok * 2 + 1] = (float)i2;
      atomicAdd(&scnt[i1], 1.f);
      atomicAdd(&scnt[i2], 1.f);
      if (m1 - m2 < TAU || m2 - m3 < TAU) {
        int slot = atomicAdd(qd, 1);
        qd[8 + slot] = tok;
      }
    }
  }
  atomicAdd(&sP[lane], psum_local);
  if (lane == 0) atomicAdd(&scomp, comp_local);
  __syncthreads();
  if (tid < 64) {
    atomicAdd(&ws[64 + tid], sP[tid]);
    atomicAdd(&ws[128 + tid], scnt[tid]);
  }
  if (tid == 0) atomicAdd(&ws[192], scomp);
}

// ---------------- K4: exact fp32 repair of margin-flagged tokens ---------------
__global__ __launch_bounds__(256) void repair_kernel(
    const float* __restrict__ x, const float* __restrict__ gate_w,
    const float* __restrict__ eb_p, float* __restrict__ ws,
    float* __restrict__ out, int N)
{
  const int tid = threadIdx.x;
  __shared__ float red[256];
  int* qd = (int*)(ws + 200);
  const int qn = qd[0];
  float* o_ts = out;
  float* o_ti = out + 2 * N;

  for (int e = blockIdx.x; e < qn; e += gridDim.x) {
    const int tok = qd[8 + e];
    const int o = tid & 63;
    const int kq = tid >> 6;
    const float* xr = x + (size_t)tok * 4096 + kq * 1024;
    const float* wr = gate_w + (size_t)o * 4096 + kq * 1024;
    float s = 0.f;
#pragma unroll 4
    for (int j = 0; j < 256; ++j) {
      const float4 xv = *(const float4*)(xr + j * 4);
      const float4 wv = *(const float4*)(wr + j * 4);
      s = fmaf(xv.x, wv.x, s); s = fmaf(xv.y, wv.y, s);
      s = fmaf(xv.z, wv.z, s); s = fmaf(xv.w, wv.w, s);
    }
    red[tid] = s;
    __syncthreads();
    if (tid < 64) {
      const float a = red[tid] + red[64 + tid] + red[128 + tid] +
                      red[192 + tid] + eb_p[tid] - ws[tid];
      const int lane = tid;
      float m1 = a; int i1 = lane;
#pragma unroll
      for (int oo = 32; oo; oo >>= 1) {
        const float ov = __shfl_xor(m1, oo, 64);
        const int oi = __shfl_xor(i1, oo, 64);
        if (ov > m1 || (ov == m1 && oi < i1)) { m1 = ov; i1 = oi; }
      }
      float m2 = (lane == i1) ? -1e30f : a; int i2 = lane;
#pragma unroll
      for (int oo = 32; oo; oo >>= 1) {
        const float ov = __shfl_xor(m2, oo, 64);
        const int oi = __shfl_xor(i2, oo, 64);
        if (ov > m2 || (ov == m2 && oi < i2)) { m2 = ov; i2 = oi; }
      }
      const float p = expf(a - m1);
      const float ssum = wsum(p);
      const float s1 = rlf(p, i1) / ssum;
      const float s2 = rlf(p, i2) / ssum;
      if (lane == 0) {
        const int i1o = (int)o_ti[tok * 2 + 0];
        const int i2o = (int)o_ti[tok * 2 + 1];
        const float inv = 1.f / (s1 + s2);
        o_ts[tok * 2 + 0] = s1 * inv;
        o_ts[tok * 2 + 1] = s2 * inv;
        o_ti[tok * 2 + 0] = (float)i1;
        o_ti[tok * 2 + 1] = (float)i2;
        if (i1o != i1 || i2o != i2) {
          atomicAdd(&ws[128 + i1o], -1.f);
          atomicAdd(&ws[128 + i2o], -1.f);
          atomicAdd(&ws[128 + i1], 1.f);
          atomicAdd(&ws[128 + i2], 1.f);
        }
      }
    }
    __syncthreads();
  }
}

// ---------------- K5: finalize aux_loss + capacity ----------------
__global__ __launch_bounds__(64) void fin_kernel(const float* __restrict__ ws,
                                                 float* __restrict__ out, int N) {
  const int e = threadIdx.x;
  const float P = ws[64 + e] / (float)N;
  const float f = ws[128 + e] / (float)(2 * N);
  const float v = wsum(f * P);
  if (e == 0) {
    out[4 * N + 0] = 64.f * v;
    float cap = 0.5f + 1.5f * (ws[192] / (float)N);
    out[4 * N + 1] = fminf(fmaxf(cap, 0.5f), 2.f);
  }
}

extern "C" void kernel_launch(void* const* d_in, const int* in_sizes, int n_in,
                              void* d_out, int out_size, void* d_ws, size_t ws_size,
                              hipStream_t stream) {
  const float* x          = (const float*)d_in[0];
  const float* gate_w     = (const float*)d_in[1];
  const float* expert_bias= (const float*)d_in[2];
  const float* cp_w1      = (const float*)d_in[3];
  const float* cp_b1      = (const float*)d_in[4];
  const float* cp_w2      = (const float*)d_in[5];
  const float* cp_b2      = (const float*)d_in[6];
  const float* load_buffer= (const float*)d_in[7];
  const float* wih0       = (const float*)d_in[8];
  const float* whh0       = (const float*)d_in[9];
  const float* bih0       = (const float*)d_in[10];
  const float* bhh0       = (const float*)d_in[11];
  const float* wih1       = (const float*)d_in[12];
  const float* whh1       = (const float*)d_in[13];
  const float* bih1       = (const float*)d_in[14];
  const float* bhh1       = (const float*)d_in[15];
  const float* head_w     = (const float*)d_in[16];
  const float* head_b     = (const float*)d_in[17];
  float* out = (float*)d_out;
  float* ws  = (float*)d_ws;
  const int N = in_sizes[0] / 4096;  // 16384 tokens

  prep_kernel<<<129, 256, 0, stream>>>(gate_w, cp_w1, load_buffer, wih0, ws);
  gemm_kernel<<<1025, 256, 0, stream>>>(x, ws, out,
                                        wih1, whh0, bih0, bhh0, whh1,
                                        bih1, bhh1, head_w, head_b, N);
  epi_kernel<<<N / 32, 256, 0, stream>>>(expert_bias, cp_b1, cp_w2, cp_b2,
                                         ws, out, N);
  repair_kernel<<<128, 256, 0, stream>>>(x, gate_w, expert_bias, ws, out, N);
  fin_kernel<<<1, 64, 0, stream>>>(ws, out, N);
}

// Round 18
// 207.863 us; speedup vs baseline: 1.0714x; 1.0714x over previous
//
#include <hip/hip_runtime.h>
#include <stdint.h>

// ---------------- ws layout ----------------
// floats: [0..63] future_load | [64..127] P sums | [128..191] cnt | [192] comp
// ints  : (ws+200): [0] qcount, [8..] queue entries
// bytes : +80000  : W frag-major image, 128 chunks x 16384 B.
// floats: +680000 : partial logits, 4 slabs of [16384][128] (plain coalesced
//   stores, one slab per K-quarter — NO atomics; epi sums slabs in fixed order)
#define IMG_OFF_BYTES 80000
#define CHUNK_IMG 16384
#define LOGITS_OFF 680000
#define SLAB 2097152
#define TAU 1e-3f

#define XLOFF 5120          // x_lo offset within an x buffer
#define BUF_STRIDE 10240    // x buffer: 64 rows x 80 B (hi) + same (lo)

typedef __attribute__((ext_vector_type(8))) short short8v;
typedef __attribute__((ext_vector_type(4))) short short4v;
typedef __attribute__((ext_vector_type(4))) float f32x4;

__device__ __forceinline__ float rlf(float v, int l) {
  return __int_as_float(__builtin_amdgcn_readlane(__float_as_int(v), l));
}
__device__ __forceinline__ float wsum(float v) {
#pragma unroll
  for (int o = 32; o; o >>= 1) v += __shfl_xor(v, o, 64);
  return v;
}
__device__ __forceinline__ float wmax(float v) {
#pragma unroll
  for (int o = 32; o; o >>= 1) v = fmaxf(v, __shfl_xor(v, o, 64));
  return v;
}
__device__ __forceinline__ unsigned short f2bf(float f) {
  unsigned u = __float_as_uint(f);
  u += 0x7fffu + ((u >> 16) & 1u);
  return (unsigned short)(u >> 16);
}
__device__ __forceinline__ float bf2f(unsigned short h) {
  return __uint_as_float(((unsigned)h) << 16);
}
__device__ __forceinline__ short8v frag8(const char* p0, const char* p1) {
  short4v a = *(const short4v*)p0;
  short4v b = *(const short4v*)p1;
  return __builtin_shufflevector(a, b, 0, 1, 2, 3, 4, 5, 6, 7);
}

// ---------------- K0: prep — zero accums, build frag-major W image ----
__global__ __launch_bounds__(256) void prep_kernel(
    const float* __restrict__ gate_w, const float* __restrict__ cp_w1,
    float* __restrict__ ws)
{
  const int c = blockIdx.x;       // chunk 0..127
  const int tid = threadIdx.x;
  if (c == 0 && tid < 144) ws[64 + tid] = 0.f;  // P, cnt, comp, queue header
  const int row = tid >> 1;       // W row (output col) 0..127
  const int half = tid & 1;       // k half: 0 -> k0..15, 1 -> k16..31
  const float* src = ((row < 64) ? (gate_w + (size_t)row * 4096)
                                 : (cp_w1 + (size_t)(row - 64) * 4096)) + c * 32 + half * 16;
  float v[16];
#pragma unroll
  for (int j = 0; j < 4; ++j) *(float4*)&v[j * 4] = *(const float4*)(src + j * 4);
  const int g = row >> 4, r15 = row & 15;
  char* img = (char*)ws + IMG_OFF_BYTES + (size_t)c * CHUNK_IMG + g * 2048;
#pragma unroll
  for (int q = 0; q < 4; ++q) {
    unsigned short h0 = f2bf(v[4 * q + 0]), h1 = f2bf(v[4 * q + 1]);
    unsigned short h2 = f2bf(v[4 * q + 2]), h3 = f2bf(v[4 * q + 3]);
    unsigned short l0 = f2bf(v[4 * q + 0] - bf2f(h0));
    unsigned short l1 = f2bf(v[4 * q + 1] - bf2f(h1));
    unsigned short l2 = f2bf(v[4 * q + 2] - bf2f(h2));
    unsigned short l3 = f2bf(v[4 * q + 3] - bf2f(h3));
    uint2 hv, lv;
    hv.x = (unsigned)h0 | ((unsigned)h1 << 16);
    hv.y = (unsigned)h2 | ((unsigned)h3 << 16);
    lv.x = (unsigned)l0 | ((unsigned)l1 << 16);
    lv.y = (unsigned)l2 | ((unsigned)l3 << 16);
    const int l = q * 16 + r15;
    *(uint2*)(img + l * 16 + half * 8) = hv;            // hi KB
    *(uint2*)(img + 1024 + l * 16 + half * 8) = lv;     // lo KB
  }
}

// ---------------- LSTM (device fn, block 0 of gemm kernel; R14-verified) ------
__device__ void lstm_device(
    char* ldsbase,
    const float* __restrict__ lb,
    const float* __restrict__ wih0, const float* __restrict__ whh0,
    const float* __restrict__ bih0, const float* __restrict__ bhh0,
    const float* __restrict__ wih1, const float* __restrict__ whh1,
    const float* __restrict__ bih1, const float* __restrict__ bhh1,
    const float* __restrict__ head_w, const float* __restrict__ head_b,
    float* __restrict__ ws, float* __restrict__ out, int N)
{
  float* seqh = (float*)ldsbase;            // 3200
  float* h1s  = seqh + 3200;                // 3200
  float* zbuf = h1s + 3200;                 // 256
  float* hbuf = zbuf + 256;                 // 64
  float* preds = hbuf + 64;                 // 640
  const int tid = threadIdx.x;
  const int lane = tid & 63;
  for (int i = tid; i < 3200; i += 256) seqh[i] = lb[i];

  float hv = 0.f;
#pragma unroll 1
  for (int L = 0; L < 2; ++L) {
    const float* wip  = L ? wih1 : wih0;
    const float* whp  = L ? whh1 : whh0;
    const float* bip  = L ? bih1 : bih0;
    const float* bhp  = L ? bhh1 : bhh0;
    const float* seqp = L ? h1s  : seqh;
    float wiR[64], whR[64];
#pragma unroll
    for (int j = 0; j < 64; j += 4) {
      *(float4*)&wiR[j] = *(const float4*)(wip + tid * 64 + j);
      *(float4*)&whR[j] = *(const float4*)(whp + tid * 64 + j);
    }
    const float bsum = bip[tid] + bhp[tid];
    float c_reg = 0.f;
    hv = 0.f;
    if (tid < 64) hbuf[tid] = 0.f;
    __syncthreads();
#pragma unroll 1
    for (int t = 0; t < 50; ++t) {
      const float xv = seqp[t * 64 + lane];
      float a0 = bsum, a1 = 0.f, a2 = 0.f, a3 = 0.f;
#pragma unroll
      for (int j = 0; j < 64; j += 4) {
        a0 = fmaf(rlf(xv, j + 0), wiR[j + 0], a0);
        a1 = fmaf(rlf(xv, j + 1), wiR[j + 1], a1);
        a2 = fmaf(rlf(xv, j + 2), wiR[j + 2], a2);
        a3 = fmaf(rlf(xv, j + 3), wiR[j + 3], a3);
      }
#pragma unroll
      for (int j = 0; j < 64; j += 4) {
        a0 = fmaf(rlf(hv, j + 0), whR[j + 0], a0);
        a1 = fmaf(rlf(hv, j + 1), whR[j + 1], a1);
        a2 = fmaf(rlf(hv, j + 2), whR[j + 2], a2);
        a3 = fmaf(rlf(hv, j + 3), whR[j + 3], a3);
      }
      zbuf[tid] = (a0 + a1) + (a2 + a3);
      __syncthreads();
      if (tid < 64) {
        const float zi = zbuf[tid], zf = zbuf[64 + tid];
        const float zg = zbuf[128 + tid], zo = zbuf[192 + tid];
        const float si = 1.f / (1.f + expf(-zi));
        const float sf = 1.f / (1.f + expf(-zf));
        const float so = 1.f / (1.f + expf(-zo));
        c_reg = sf * c_reg + si * tanhf(zg);
        const float h = so * tanhf(c_reg);
        hbuf[tid] = h;
        if (L == 0) h1s[t * 64 + tid] = h;
      }
      __syncthreads();
      hv = hbuf[lane];
    }
    __syncthreads();
  }
  for (int o = tid; o < 640; o += 256) {
    const float* hw = head_w + o * 64;
    float a0 = 0.f, a1 = 0.f, a2 = 0.f, a3 = 0.f;
#pragma unroll
    for (int j = 0; j < 64; j += 4) {
      a0 = fmaf(rlf(hv, j + 0), hw[j + 0], a0);
      a1 = fmaf(rlf(hv, j + 1), hw[j + 1], a1);
      a2 = fmaf(rlf(hv, j + 2), hw[j + 2], a2);
      a3 = fmaf(rlf(hv, j + 3), hw[j + 3], a3);
    }
    preds[o] = (a0 + a1) + (a2 + a3) + head_b[o];
  }
  __syncthreads();
  if (tid < 64) {
    float m = 0.f;
#pragma unroll
    for (int h = 0; h < 10; ++h) m += preds[tid * 10 + h];
    m = m / 10.f;
    const float mx = wmax(m);
    const float p = expf(m - mx);
    const float s = wsum(p);
    const float flv = p / s;
    ws[tid] = flv;
    out[4 * N + 2 + tid] = flv;
  }
}

// ---------------- K2: split-K(x4) bf16-split MFMA GEMM, W direct-to-reg -------
// K-loop: R14 champion structure verbatim. Epilogue: R10-verified LDS transpose
// + coalesced per-K-quarter slab stores (ZERO global atomics — removes the
// 8.4M cross-XCD atomicAdd tail that every dispatch since R7 carried).
__global__ __launch_bounds__(256, 1) void gemm_kernel(
    const float* __restrict__ x, float* __restrict__ ws, float* __restrict__ out,
    const float* __restrict__ lb,
    const float* __restrict__ wih0, const float* __restrict__ whh0,
    const float* __restrict__ bih0, const float* __restrict__ bhh0,
    const float* __restrict__ wih1, const float* __restrict__ whh1,
    const float* __restrict__ bih1, const float* __restrict__ bhh1,
    const float* __restrict__ head_w, const float* __restrict__ head_b,
    int N)
{
  __shared__ __align__(16) char lds[34048];  // LSTM 29440; gemm: 2x10240 + souts 33792
  if (blockIdx.x == 0) {
    lstm_device(lds, lb, wih0, whh0, bih0, bhh0, wih1, whh1, bih1, bhh1,
                head_w, head_b, ws, out, N);
    return;
  }
  const int b = blockIdx.x - 1;       // 0..1023
  const int tb = (b & 255) * 64;      // token tile
  const int kq = b >> 8;              // K-quarter 0..3
  const int ck0 = kq * 32;            // start chunk
  const int tid = threadIdx.x;
  const int lane = tid & 63;
  const int wv = __builtin_amdgcn_readfirstlane(tid >> 6);  // 0..3
  const int r15 = lane & 15;
  const int fo = (lane >> 4) * 8;     // frag byte offset within 64B row
  const int row = tid >> 2;           // x staging row 0..63
  const int kslot = tid & 3;          // 8-float group
  const float* xsrc = x + (size_t)(tb + row) * 4096 + kslot * 8;
  const char* wimg = (const char*)ws + IMG_OFF_BYTES;
  char* buf0 = lds;
  char* buf1 = lds + BUF_STRIDE;

  f32x4 acc[4][2];
#pragma unroll
  for (int mi = 0; mi < 4; ++mi)
#pragma unroll
    for (int ni = 0; ni < 2; ++ni) acc[mi][ni] = (f32x4)0.f;

  float xa[8], xb[8];
  short8v wh[2], wl[2];

#define LOADX(R, C)                                                        \
  { *(float4*)&R[0] = *(const float4*)(xsrc + (size_t)(C) * 32);           \
    *(float4*)&R[4] = *(const float4*)(xsrc + (size_t)(C) * 32 + 4); }

#define WRITEX(R, BASE)                                                    \
  { uint4 hv, lv; unsigned hu[4], lu[4];                                   \
    _Pragma("unroll")                                                      \
    for (int i = 0; i < 4; ++i) {                                          \
      unsigned short h0 = f2bf(R[2 * i]), h1 = f2bf(R[2 * i + 1]);         \
      unsigned short l0 = f2bf(R[2 * i] - bf2f(h0));                       \
      unsigned short l1 = f2bf(R[2 * i + 1] - bf2f(h1));                   \
      hu[i] = (unsigned)h0 | ((unsigned)h1 << 16);                         \
      lu[i] = (unsigned)l0 | ((unsigned)l1 << 16);                         \
    }                                                                      \
    hv.x = hu[0]; hv.y = hu[1]; hv.z = hu[2]; hv.w = hu[3];                \
    lv.x = lu[0]; lv.y = lu[1]; lv.z = lu[2]; lv.w = lu[3];                \
    *(uint4*)((BASE) + row * 80 + kslot * 16) = hv;                        \
    *(uint4*)((BASE) + XLOFF + row * 80 + kslot * 16) = lv; }

#define WLOAD(C)                                                           \
  { const char* wb = wimg + (size_t)(C) * CHUNK_IMG + wv * 4096 + lane * 16; \
    wh[0] = *(const short8v*)wb;                                           \
    wl[0] = *(const short8v*)(wb + 1024);                                  \
    wh[1] = *(const short8v*)(wb + 2048);                                  \
    wl[1] = *(const short8v*)(wb + 3072); }

#define COMPUTE(BASE)                                                      \
  { short8v xh[4], xl[4];                                                  \
    _Pragma("unroll")                                                      \
    for (int mi = 0; mi < 4; ++mi) {                                       \
      const char* p = (BASE) + (mi * 16 + r15) * 80 + fo;                  \
      xh[mi] = frag8(p, p + 32);                                           \
      xl[mi] = frag8(p + XLOFF, p + XLOFF + 32);                           \
    }                                                                      \
    _Pragma("unroll")                                                      \
    for (int mi = 0; mi < 4; ++mi)                                         \
      _Pragma("unroll")                                                    \
      for (int ni = 0; ni < 2; ++ni) {                                     \
        acc[mi][ni] = __builtin_amdgcn_mfma_f32_16x16x32_bf16(             \
            xh[mi], wh[ni], acc[mi][ni], 0, 0, 0);                         \
        acc[mi][ni] = __builtin_amdgcn_mfma_f32_16x16x32_bf16(             \
            xh[mi], wl[ni], acc[mi][ni], 0, 0, 0);                         \
        acc[mi][ni] = __builtin_amdgcn_mfma_f32_16x16x32_bf16(             \
            xl[mi], wh[ni], acc[mi][ni], 0, 0, 0);                         \
      } }

  // prologue
  LOADX(xa, ck0);
  LOADX(xb, ck0 + 1);
  WRITEX(xa, buf0);
  __syncthreads();

#pragma unroll 1
  for (int cc = 0; cc < 16; ++cc) {
    const int c0 = ck0 + 2 * cc, c1 = c0 + 1;
    // even chunk: compute buf0
    WLOAD(c0);
    if (cc < 15) LOADX(xa, c0 + 2);
    COMPUTE(buf0);
    WRITEX(xb, buf1);
    __syncthreads();
    // odd chunk: compute buf1
    WLOAD(c1);
    if (cc < 15) LOADX(xb, c1 + 2);
    COMPUTE(buf1);
    if (cc < 15) WRITEX(xa, buf0);
    __syncthreads();
  }

  // epilogue (R10-verified): LDS transpose acc -> souts[64][132], then fully
  // coalesced dwordx4 stores into this K-quarter's private slab. No atomics.
  float (*souts)[132] = (float(*)[132])lds;   // loop's final barrier ordered reads
#pragma unroll
  for (int mi = 0; mi < 4; ++mi)
#pragma unroll
    for (int ni = 0; ni < 2; ++ni)
#pragma unroll
      for (int r = 0; r < 4; ++r)
        souts[mi * 16 + (lane >> 4) * 4 + r][wv * 32 + ni * 16 + r15] =
            acc[mi][ni][r];
  __syncthreads();
  {
    float* slab = ws + LOGITS_OFF + (size_t)kq * SLAB;
    const int srow = tid >> 2, sq = tid & 3;     // 64 rows x 4 quarters of 32 floats
    float4* dst = (float4*)(slab + (size_t)(tb + srow) * 128 + sq * 32);
    const float4* srcp = (const float4*)&souts[srow][sq * 32];
#pragma unroll
    for (int i = 0; i < 8; ++i) dst[i] = srcp[i];
  }
#undef LOADX
#undef WRITEX
#undef WLOAD
#undef COMPUTE
}

// ---------------- K3: epilogue — sum 4 slabs, softmax, top-2, margins, sums ----
__global__ __launch_bounds__(256) void epi_kernel(
    const float* __restrict__ eb_p, const float* __restrict__ cp_b1,
    const float* __restrict__ cp_w2, const float* __restrict__ cp_b2,
    float* __restrict__ ws, float* __restrict__ out, int N)
{
  const int tid = threadIdx.x;
  const int lane = tid & 63;
  const int wv = __builtin_amdgcn_readfirstlane(tid >> 6);
  const int tb = blockIdx.x * 32;
  const float* lg = ws + LOGITS_OFF;
  int* qd = (int*)(ws + 200);
  __shared__ float sP[64];
  __shared__ float scnt[64];
  __shared__ float scomp;
  if (tid < 64) { sP[tid] = 0.f; scnt[tid] = 0.f; }
  if (tid == 0) scomp = 0.f;
  __syncthreads();

  const float eb = eb_p[lane];
  const float fl = ws[lane];
  const float cb1 = cp_b1[lane];
  const float cw2 = cp_w2[lane];
  const float cb2 = cp_b2[0];
  float psum_local = 0.f, comp_local = 0.f;
  float* o_ts = out;
  float* o_ti = out + 2 * N;

#pragma unroll 1
  for (int tt = 0; tt < 8; ++tt) {
    const int tok = tb + wv * 8 + tt;
    const size_t base = (size_t)tok * 128;
    // fixed-order 4-slab sum (deterministic)
    const float lgv = ((lg[base + lane] + lg[SLAB + base + lane]) +
                       (lg[2 * SLAB + base + lane] + lg[3 * SLAB + base + lane]));
    const float lc  = ((lg[base + 64 + lane] + lg[SLAB + base + 64 + lane]) +
                       (lg[2 * SLAB + base + 64 + lane] + lg[3 * SLAB + base + 64 + lane]));
    float rr = fmaxf(lc + cb1, 0.f) * cw2;
    rr = wsum(rr);
    const float comp = 1.f / (1.f + expf(-(rr + cb2)));
    comp_local += comp;
    const float a = lgv + eb - fl;
    float m1 = a; int i1 = lane;
#pragma unroll
    for (int o = 32; o; o >>= 1) {
      const float ov = __shfl_xor(m1, o, 64);
      const int oi = __shfl_xor(i1, o, 64);
      if (ov > m1 || (ov == m1 && oi < i1)) { m1 = ov; i1 = oi; }
    }
    float m2 = (lane == i1) ? -1e30f : a; int i2 = lane;
#pragma unroll
    for (int o = 32; o; o >>= 1) {
      const float ov = __shfl_xor(m2, o, 64);
      const int oi = __shfl_xor(i2, o, 64);
      if (ov > m2 || (ov == m2 && oi < i2)) { m2 = ov; i2 = oi; }
    }
    float m3 = (lane == i1 || lane == i2) ? -1e30f : a;
#pragma unroll
    for (int o = 32; o; o >>= 1) m3 = fmaxf(m3, __shfl_xor(m3, o, 64));
    const float p = expf(a - m1);
    const float ssum = wsum(p);
    const float prob = p / ssum;
    psum_local += prob;
    const float s1 = rlf(prob, i1);
    const float s2 = rlf(prob, i2);
    if (lane == 0) {
      const float inv = 1.f / (s1 + s2);
      o_ts[tok * 2 + 0] = s1 * inv;
      o_ts[tok * 2 + 1] = s2 * inv;
      o_ti[tok * 2 + 0] = (float)i1;
      o_ti[tok * 2 + 1] = (float)i2;
      atomicAdd(&scnt[i1], 1.f);
      atomicAdd(&scnt[i2], 1.f);
      if (m1 - m2 < TAU || m2 - m3 < TAU) {
        int slot = atomicAdd(qd, 1);
        qd[8 + slot] = tok;
      }
    }
  }
  atomicAdd(&sP[lane], psum_local);
  if (lane == 0) atomicAdd(&scomp, comp_local);
  __syncthreads();
  if (tid < 64) {
    atomicAdd(&ws[64 + tid], sP[tid]);
    atomicAdd(&ws[128 + tid], scnt[tid]);
  }
  if (tid == 0) atomicAdd(&ws[192], scomp);
}

// ---------------- K4: exact fp32 repair of margin-flagged tokens ---------------
__global__ __launch_bounds__(256) void repair_kernel(
    const float* __restrict__ x, const float* __restrict__ gate_w,
    const float* __restrict__ eb_p, float* __restrict__ ws,
    float* __restrict__ out, int N)
{
  const int tid = threadIdx.x;
  __shared__ float red[256];
  int* qd = (int*)(ws + 200);
  const int qn = qd[0];
  float* o_ts = out;
  float* o_ti = out + 2 * N;

  for (int e = blockIdx.x; e < qn; e += gridDim.x) {
    const int tok = qd[8 + e];
    const int o = tid & 63;
    const int kq = tid >> 6;
    const float* xr = x + (size_t)tok * 4096 + kq * 1024;
    const float* wr = gate_w + (size_t)o * 4096 + kq * 1024;
    float s = 0.f;
#pragma unroll 4
    for (int j = 0; j < 256; ++j) {
      const float4 xv = *(const float4*)(xr + j * 4);
      const float4 wv = *(const float4*)(wr + j * 4);
      s = fmaf(xv.x, wv.x, s); s = fmaf(xv.y, wv.y, s);
      s = fmaf(xv.z, wv.z, s); s = fmaf(xv.w, wv.w, s);
    }
    red[tid] = s;
    __syncthreads();
    if (tid < 64) {
      const float a = red[tid] + red[64 + tid] + red[128 + tid] +
                      red[192 + tid] + eb_p[tid] - ws[tid];
      const int lane = tid;
      float m1 = a; int i1 = lane;
#pragma unroll
      for (int oo = 32; oo; oo >>= 1) {
        const float ov = __shfl_xor(m1, oo, 64);
        const int oi = __shfl_xor(i1, oo, 64);
        if (ov > m1 || (ov == m1 && oi < i1)) { m1 = ov; i1 = oi; }
      }
      float m2 = (lane == i1) ? -1e30f : a; int i2 = lane;
#pragma unroll
      for (int oo = 32; oo; oo >>= 1) {
        const float ov = __shfl_xor(m2, oo, 64);
        const int oi = __shfl_xor(i2, oo, 64);
        if (ov > m2 || (ov == m2 && oi < i2)) { m2 = ov; i2 = oi; }
      }
      const float p = expf(a - m1);
      const float ssum = wsum(p);
      const float s1 = rlf(p, i1) / ssum;
      const float s2 = rlf(p, i2) / ssum;
      if (lane == 0) {
        const int i1o = (int)o_ti[tok * 2 + 0];
        const int i2o = (int)o_ti[tok * 2 + 1];
        const float inv = 1.f / (s1 + s2);
        o_ts[tok * 2 + 0] = s1 * inv;
        o_ts[tok * 2 + 1] = s2 * inv;
        o_ti[tok * 2 + 0] = (float)i1;
        o_ti[tok * 2 + 1] = (float)i2;
        if (i1o != i1 || i2o != i2) {
          atomicAdd(&ws[128 + i1o], -1.f);
          atomicAdd(&ws[128 + i2o], -1.f);
          atomicAdd(&ws[128 + i1], 1.f);
          atomicAdd(&ws[128 + i2], 1.f);
        }
      }
    }
    __syncthreads();
  }
}

// ---------------- K5: finalize aux_loss + capacity ----------------
__global__ __launch_bounds__(64) void fin_kernel(const float* __restrict__ ws,
                                                 float* __restrict__ out, int N) {
  const int e = threadIdx.x;
  const float P = ws[64 + e] / (float)N;
  const float f = ws[128 + e] / (float)(2 * N);
  const float v = wsum(f * P);
  if (e == 0) {
    out[4 * N + 0] = 64.f * v;
    float cap = 0.5f + 1.5f * (ws[192] / (float)N);
    out[4 * N + 1] = fminf(fmaxf(cap, 0.5f), 2.f);
  }
}

extern "C" void kernel_launch(void* const* d_in, const int* in_sizes, int n_in,
                              void* d_out, int out_size, void* d_ws, size_t ws_size,
                              hipStream_t stream) {
  const float* x          = (const float*)d_in[0];
  const float* gate_w     = (const float*)d_in[1];
  const float* expert_bias= (const float*)d_in[2];
  const float* cp_w1      = (const float*)d_in[3];
  const float* cp_b1      = (const float*)d_in[4];
  const float* cp_w2      = (const float*)d_in[5];
  const float* cp_b2      = (const float*)d_in[6];
  const float* load_buffer= (const float*)d_in[7];
  const float* wih0       = (const float*)d_in[8];
  const float* whh0       = (const float*)d_in[9];
  const float* bih0       = (const float*)d_in[10];
  const float* bhh0       = (const float*)d_in[11];
  const float* wih1       = (const float*)d_in[12];
  const float* whh1       = (const float*)d_in[13];
  const float* bih1       = (const float*)d_in[14];
  const float* bhh1       = (const float*)d_in[15];
  const float* head_w     = (const float*)d_in[16];
  const float* head_b     = (const float*)d_in[17];
  float* out = (float*)d_out;
  float* ws  = (float*)d_ws;
  const int N = in_sizes[0] / 4096;  // 16384 tokens

  prep_kernel<<<128, 256, 0, stream>>>(gate_w, cp_w1, ws);
  gemm_kernel<<<1025, 256, 0, stream>>>(x, ws, out, load_buffer,
                                        wih0, whh0, bih0, bhh0,
                                        wih1, whh1, bih1, bhh1,
                                        head_w, head_b, N);
  epi_kernel<<<N / 32, 256, 0, stream>>>(expert_bias, cp_b1, cp_w2, cp_b2,
                                         ws, out, N);
  repair_kernel<<<128, 256, 0, stream>>>(x, gate_w, expert_bias, ws, out, N);
  fin_kernel<<<1, 64, 0, stream>>>(ws, out, N);
}

// Round 19
// 191.571 us; speedup vs baseline: 1.1625x; 1.0850x over previous
//
#include <hip/hip_runtime.h>
#include <stdint.h>

// ---------------- ws layout ----------------
// floats: [0..63] future_load | [64..127] P sums | [128..191] cnt | [192] comp
// ints  : (ws+200): [0] qcount, [8..] queue entries
// bytes : +80000  : W frag-major image, 128 chunks x 16384 B.
// floats: +680000 : logits [16384][128] (atomic-accumulated, zeroed by prep)
#define IMG_OFF_BYTES 80000
#define CHUNK_IMG 16384
#define LOGITS_OFF 680000
#define TAU 1e-3f

#define XLOFF 5120          // x_lo offset within an x buffer
#define BUF_STRIDE 10240    // x buffer: 64 rows x 80 B (hi) + same (lo)

typedef __attribute__((ext_vector_type(8))) short short8v;
typedef __attribute__((ext_vector_type(4))) short short4v;
typedef __attribute__((ext_vector_type(4))) float f32x4;

__device__ __forceinline__ float rlf(float v, int l) {
  return __int_as_float(__builtin_amdgcn_readlane(__float_as_int(v), l));
}
__device__ __forceinline__ float wsum(float v) {
#pragma unroll
  for (int o = 32; o; o >>= 1) v += __shfl_xor(v, o, 64);
  return v;
}
__device__ __forceinline__ float wmax(float v) {
#pragma unroll
  for (int o = 32; o; o >>= 1) v = fmaxf(v, __shfl_xor(v, o, 64));
  return v;
}
__device__ __forceinline__ unsigned short f2bf(float f) {
  unsigned u = __float_as_uint(f);
  u += 0x7fffu + ((u >> 16) & 1u);
  return (unsigned short)(u >> 16);
}
__device__ __forceinline__ float bf2f(unsigned short h) {
  return __uint_as_float(((unsigned)h) << 16);
}
__device__ __forceinline__ short8v frag8(const char* p0, const char* p1) {
  short4v a = *(const short4v*)p0;
  short4v b = *(const short4v*)p1;
  return __builtin_shufflevector(a, b, 0, 1, 2, 3, 4, 5, 6, 7);
}

// ---------------- K0: prep — zero accums+logits, build frag-major W image ----
__global__ __launch_bounds__(256) void prep_kernel(
    const float* __restrict__ gate_w, const float* __restrict__ cp_w1,
    float* __restrict__ ws)
{
  const int c = blockIdx.x;       // chunk 0..127
  const int tid = threadIdx.x;
  if (c == 0 && tid < 144) ws[64 + tid] = 0.f;  // P, cnt, comp, queue header
  {  // zero this block's logits slab (16384 floats)
    float4 z = make_float4(0.f, 0.f, 0.f, 0.f);
    float4* lz = (float4*)(ws + LOGITS_OFF + c * 16384);
#pragma unroll
    for (int i = 0; i < 16; ++i) lz[tid + i * 256] = z;
  }
  const int row = tid >> 1;       // W row (output col) 0..127
  const int half = tid & 1;       // k half: 0 -> k0..15, 1 -> k16..31
  const float* src = ((row < 64) ? (gate_w + (size_t)row * 4096)
                                 : (cp_w1 + (size_t)(row - 64) * 4096)) + c * 32 + half * 16;
  float v[16];
#pragma unroll
  for (int j = 0; j < 4; ++j) *(float4*)&v[j * 4] = *(const float4*)(src + j * 4);
  const int g = row >> 4, r15 = row & 15;
  char* img = (char*)ws + IMG_OFF_BYTES + (size_t)c * CHUNK_IMG + g * 2048;
#pragma unroll
  for (int q = 0; q < 4; ++q) {
    unsigned short h0 = f2bf(v[4 * q + 0]), h1 = f2bf(v[4 * q + 1]);
    unsigned short h2 = f2bf(v[4 * q + 2]), h3 = f2bf(v[4 * q + 3]);
    unsigned short l0 = f2bf(v[4 * q + 0] - bf2f(h0));
    unsigned short l1 = f2bf(v[4 * q + 1] - bf2f(h1));
    unsigned short l2 = f2bf(v[4 * q + 2] - bf2f(h2));
    unsigned short l3 = f2bf(v[4 * q + 3] - bf2f(h3));
    uint2 hv, lv;
    hv.x = (unsigned)h0 | ((unsigned)h1 << 16);
    hv.y = (unsigned)h2 | ((unsigned)h3 << 16);
    lv.x = (unsigned)l0 | ((unsigned)l1 << 16);
    lv.y = (unsigned)l2 | ((unsigned)l3 << 16);
    const int l = q * 16 + r15;
    *(uint2*)(img + l * 16 + half * 8) = hv;            // hi KB
    *(uint2*)(img + 1024 + l * 16 + half * 8) = lv;     // lo KB
  }
}

// ---------------- LSTM (device fn, block 0 of gemm kernel; R14-verified) ------
__device__ void lstm_device(
    char* ldsbase,
    const float* __restrict__ lb,
    const float* __restrict__ wih0, const float* __restrict__ whh0,
    const float* __restrict__ bih0, const float* __restrict__ bhh0,
    const float* __restrict__ wih1, const float* __restrict__ whh1,
    const float* __restrict__ bih1, const float* __restrict__ bhh1,
    const float* __restrict__ head_w, const float* __restrict__ head_b,
    float* __restrict__ ws, float* __restrict__ out, int N)
{
  float* seqh = (float*)ldsbase;            // 3200
  float* h1s  = seqh + 3200;                // 3200
  float* zbuf = h1s + 3200;                 // 256
  float* hbuf = zbuf + 256;                 // 64
  float* preds = hbuf + 64;                 // 640
  const int tid = threadIdx.x;
  const int lane = tid & 63;
  for (int i = tid; i < 3200; i += 256) seqh[i] = lb[i];

  float hv = 0.f;
#pragma unroll 1
  for (int L = 0; L < 2; ++L) {
    const float* wip  = L ? wih1 : wih0;
    const float* whp  = L ? whh1 : whh0;
    const float* bip  = L ? bih1 : bih0;
    const float* bhp  = L ? bhh1 : bhh0;
    const float* seqp = L ? h1s  : seqh;
    float wiR[64], whR[64];
#pragma unroll
    for (int j = 0; j < 64; j += 4) {
      *(float4*)&wiR[j] = *(const float4*)(wip + tid * 64 + j);
      *(float4*)&whR[j] = *(const float4*)(whp + tid * 64 + j);
    }
    const float bsum = bip[tid] + bhp[tid];
    float c_reg = 0.f;
    hv = 0.f;
    if (tid < 64) hbuf[tid] = 0.f;
    __syncthreads();
#pragma unroll 1
    for (int t = 0; t < 50; ++t) {
      const float xv = seqp[t * 64 + lane];
      float a0 = bsum, a1 = 0.f, a2 = 0.f, a3 = 0.f;
#pragma unroll
      for (int j = 0; j < 64; j += 4) {
        a0 = fmaf(rlf(xv, j + 0), wiR[j + 0], a0);
        a1 = fmaf(rlf(xv, j + 1), wiR[j + 1], a1);
        a2 = fmaf(rlf(xv, j + 2), wiR[j + 2], a2);
        a3 = fmaf(rlf(xv, j + 3), wiR[j + 3], a3);
      }
#pragma unroll
      for (int j = 0; j < 64; j += 4) {
        a0 = fmaf(rlf(hv, j + 0), whR[j + 0], a0);
        a1 = fmaf(rlf(hv, j + 1), whR[j + 1], a1);
        a2 = fmaf(rlf(hv, j + 2), whR[j + 2], a2);
        a3 = fmaf(rlf(hv, j + 3), whR[j + 3], a3);
      }
      zbuf[tid] = (a0 + a1) + (a2 + a3);
      __syncthreads();
      if (tid < 64) {
        const float zi = zbuf[tid], zf = zbuf[64 + tid];
        const float zg = zbuf[128 + tid], zo = zbuf[192 + tid];
        const float si = 1.f / (1.f + expf(-zi));
        const float sf = 1.f / (1.f + expf(-zf));
        const float so = 1.f / (1.f + expf(-zo));
        c_reg = sf * c_reg + si * tanhf(zg);
        const float h = so * tanhf(c_reg);
        hbuf[tid] = h;
        if (L == 0) h1s[t * 64 + tid] = h;
      }
      __syncthreads();
      hv = hbuf[lane];
    }
    __syncthreads();
  }
  for (int o = tid; o < 640; o += 256) {
    const float* hw = head_w + o * 64;
    float a0 = 0.f, a1 = 0.f, a2 = 0.f, a3 = 0.f;
#pragma unroll
    for (int j = 0; j < 64; j += 4) {
      a0 = fmaf(rlf(hv, j + 0), hw[j + 0], a0);
      a1 = fmaf(rlf(hv, j + 1), hw[j + 1], a1);
      a2 = fmaf(rlf(hv, j + 2), hw[j + 2], a2);
      a3 = fmaf(rlf(hv, j + 3), hw[j + 3], a3);
    }
    preds[o] = (a0 + a1) + (a2 + a3) + head_b[o];
  }
  __syncthreads();
  if (tid < 64) {
    float m = 0.f;
#pragma unroll
    for (int h = 0; h < 10; ++h) m += preds[tid * 10 + h];
    m = m / 10.f;
    const float mx = wmax(m);
    const float p = expf(m - mx);
    const float s = wsum(p);
    const float flv = p / s;
    ws[tid] = flv;
    out[4 * N + 2 + tid] = flv;
  }
}

// ---------------- K2: split-K(x4) bf16-split MFMA GEMM, 4-deep x prefetch -----
// R14 champion structure; ONE change: x register pipeline deepened 2 -> 4
// chunks (xa..xd rotate; phase c computes chunk c, WRITEXes chunk c+1, loads
// chunk c+4). Load->use distance 1 -> 3 phases; ~3x outstanding x loads.
__global__ __launch_bounds__(256, 1) void gemm_kernel(
    const float* __restrict__ x, float* __restrict__ ws, float* __restrict__ out,
    const float* __restrict__ lb,
    const float* __restrict__ wih0, const float* __restrict__ whh0,
    const float* __restrict__ bih0, const float* __restrict__ bhh0,
    const float* __restrict__ wih1, const float* __restrict__ whh1,
    const float* __restrict__ bih1, const float* __restrict__ bhh1,
    const float* __restrict__ head_w, const float* __restrict__ head_b,
    int N)
{
  __shared__ __align__(16) char lds[30720];  // LSTM needs 29440; gemm uses 20480
  if (blockIdx.x == 0) {
    lstm_device(lds, lb, wih0, whh0, bih0, bhh0, wih1, whh1, bih1, bhh1,
                head_w, head_b, ws, out, N);
    return;
  }
  const int b = blockIdx.x - 1;       // 0..1023
  const int tb = (b & 255) * 64;      // token tile
  const int ck0 = (b >> 8) * 32;      // K-quarter start chunk
  const int tid = threadIdx.x;
  const int lane = tid & 63;
  const int wv = __builtin_amdgcn_readfirstlane(tid >> 6);  // 0..3
  const int r15 = lane & 15;
  const int fo = (lane >> 4) * 8;     // frag byte offset within 64B row
  const int row = tid >> 2;           // x staging row 0..63
  const int kslot = tid & 3;          // 8-float group
  const float* xsrc = x + (size_t)(tb + row) * 4096 + kslot * 8;
  const char* wimg = (const char*)ws + IMG_OFF_BYTES;
  char* buf0 = lds;
  char* buf1 = lds + BUF_STRIDE;

  f32x4 acc[4][2];
#pragma unroll
  for (int mi = 0; mi < 4; ++mi)
#pragma unroll
    for (int ni = 0; ni < 2; ++ni) acc[mi][ni] = (f32x4)0.f;

  float xa[8], xb[8], xc[8], xd[8];
  short8v wh[2], wl[2];

#define LOADX(R, C)                                                        \
  { *(float4*)&R[0] = *(const float4*)(xsrc + (size_t)(C) * 32);           \
    *(float4*)&R[4] = *(const float4*)(xsrc + (size_t)(C) * 32 + 4); }

#define WRITEX(R, BASE)                                                    \
  { uint4 hv, lv; unsigned hu[4], lu[4];                                   \
    _Pragma("unroll")                                                      \
    for (int i = 0; i < 4; ++i) {                                          \
      unsigned short h0 = f2bf(R[2 * i]), h1 = f2bf(R[2 * i + 1]);         \
      unsigned short l0 = f2bf(R[2 * i] - bf2f(h0));                       \
      unsigned short l1 = f2bf(R[2 * i + 1] - bf2f(h1));                   \
      hu[i] = (unsigned)h0 | ((unsigned)h1 << 16);                         \
      lu[i] = (unsigned)l0 | ((unsigned)l1 << 16);                         \
    }                                                                      \
    hv.x = hu[0]; hv.y = hu[1]; hv.z = hu[2]; hv.w = hu[3];                \
    lv.x = lu[0]; lv.y = lu[1]; lv.z = lu[2]; lv.w = lu[3];                \
    *(uint4*)((BASE) + row * 80 + kslot * 16) = hv;                        \
    *(uint4*)((BASE) + XLOFF + row * 80 + kslot * 16) = lv; }

#define WLOAD(C)                                                           \
  { const char* wb = wimg + (size_t)(C) * CHUNK_IMG + wv * 4096 + lane * 16; \
    wh[0] = *(const short8v*)wb;                                           \
    wl[0] = *(const short8v*)(wb + 1024);                                  \
    wh[1] = *(const short8v*)(wb + 2048);                                  \
    wl[1] = *(const short8v*)(wb + 3072); }

#define COMPUTE(BASE)                                                      \
  { short8v xh[4], xl[4];                                                  \
    _Pragma("unroll")                                                      \
    for (int mi = 0; mi < 4; ++mi) {                                       \
      const char* p = (BASE) + (mi * 16 + r15) * 80 + fo;                  \
      xh[mi] = frag8(p, p + 32);                                           \
      xl[mi] = frag8(p + XLOFF, p + XLOFF + 32);                           \
    }                                                                      \
    _Pragma("unroll")                                                      \
    for (int mi = 0; mi < 4; ++mi)                                         \
      _Pragma("unroll")                                                    \
      for (int ni = 0; ni < 2; ++ni) {                                     \
        acc[mi][ni] = __builtin_amdgcn_mfma_f32_16x16x32_bf16(             \
            xh[mi], wh[ni], acc[mi][ni], 0, 0, 0);                         \
        acc[mi][ni] = __builtin_amdgcn_mfma_f32_16x16x32_bf16(             \
            xh[mi], wl[ni], acc[mi][ni], 0, 0, 0);                         \
        acc[mi][ni] = __builtin_amdgcn_mfma_f32_16x16x32_bf16(             \
            xl[mi], wh[ni], acc[mi][ni], 0, 0, 0);                         \
      } }

  // prologue: 4-deep x pipeline
  LOADX(xa, ck0);
  LOADX(xb, ck0 + 1);
  LOADX(xc, ck0 + 2);
  LOADX(xd, ck0 + 3);
  WRITEX(xa, buf0);
  __syncthreads();

#pragma unroll 1
  for (int cc = 0; cc < 8; ++cc) {
    const int c0 = ck0 + 4 * cc;
    // phase 0: chunk c0 (buf0); write xb->buf1; load xa <- c0+4
    WLOAD(c0);
    if (cc < 7) LOADX(xa, c0 + 4);
    COMPUTE(buf0);
    WRITEX(xb, buf1);
    __syncthreads();
    // phase 1: chunk c0+1 (buf1); write xc->buf0; load xb <- c0+5
    WLOAD(c0 + 1);
    if (cc < 7) LOADX(xb, c0 + 5);
    COMPUTE(buf1);
    WRITEX(xc, buf0);
    __syncthreads();
    // phase 2: chunk c0+2 (buf0); write xd->buf1; load xc <- c0+6
    WLOAD(c0 + 2);
    if (cc < 7) LOADX(xc, c0 + 6);
    COMPUTE(buf0);
    WRITEX(xd, buf1);
    __syncthreads();
    // phase 3: chunk c0+3 (buf1); write xa->buf0; load xd <- c0+7
    WLOAD(c0 + 3);
    if (cc < 7) LOADX(xd, c0 + 7);
    COMPUTE(buf1);
    if (cc < 7) WRITEX(xa, buf0);
    __syncthreads();
  }

  // atomic-accumulate partial logits (4 contributions/address; jitter ~1e-6 << TAU)
  float* lg = ws + LOGITS_OFF;
#pragma unroll
  for (int mi = 0; mi < 4; ++mi)
#pragma unroll
    for (int ni = 0; ni < 2; ++ni)
#pragma unroll
      for (int r = 0; r < 4; ++r) {
        const int tokrow = tb + mi * 16 + (lane >> 4) * 4 + r;
        const int col = wv * 32 + ni * 16 + r15;
        atomicAdd(&lg[(size_t)tokrow * 128 + col], acc[mi][ni][r]);
      }
#undef LOADX
#undef WRITEX
#undef WLOAD
#undef COMPUTE
}

// ---------------- K3: epilogue — softmax, top-2, margins->queue, partial sums --
__global__ __launch_bounds__(256) void epi_kernel(
    const float* __restrict__ eb_p, const float* __restrict__ cp_b1,
    const float* __restrict__ cp_w2, const float* __restrict__ cp_b2,
    float* __restrict__ ws, float* __restrict__ out, int N)
{
  const int tid = threadIdx.x;
  const int lane = tid & 63;
  const int wv = __builtin_amdgcn_readfirstlane(tid >> 6);
  const int tb = blockIdx.x * 32;
  const float* lg = ws + LOGITS_OFF;
  int* qd = (int*)(ws + 200);
  __shared__ float sP[64];
  __shared__ float scnt[64];
  __shared__ float scomp;
  if (tid < 64) { sP[tid] = 0.f; scnt[tid] = 0.f; }
  if (tid == 0) scomp = 0.f;
  __syncthreads();

  const float eb = eb_p[lane];
  const float fl = ws[lane];
  const float cb1 = cp_b1[lane];
  const float cw2 = cp_w2[lane];
  const float cb2 = cp_b2[0];
  float psum_local = 0.f, comp_local = 0.f;
  float* o_ts = out;
  float* o_ti = out + 2 * N;

#pragma unroll 1
  for (int tt = 0; tt < 8; ++tt) {
    const int tok = tb + wv * 8 + tt;
    const float lgv = lg[(size_t)tok * 128 + lane];
    const float lc  = lg[(size_t)tok * 128 + 64 + lane];
    float rr = fmaxf(lc + cb1, 0.f) * cw2;
    rr = wsum(rr);
    const float comp = 1.f / (1.f + expf(-(rr + cb2)));
    comp_local += comp;
    const float a = lgv + eb - fl;
    float m1 = a; int i1 = lane;
#pragma unroll
    for (int o = 32; o; o >>= 1) {
      const float ov = __shfl_xor(m1, o, 64);
      const int oi = __shfl_xor(i1, o, 64);
      if (ov > m1 || (ov == m1 && oi < i1)) { m1 = ov; i1 = oi; }
    }
    float m2 = (lane == i1) ? -1e30f : a; int i2 = lane;
#pragma unroll
    for (int o = 32; o; o >>= 1) {
      const float ov = __shfl_xor(m2, o, 64);
      const int oi = __shfl_xor(i2, o, 64);
      if (ov > m2 || (ov == m2 && oi < i2)) { m2 = ov; i2 = oi; }
    }
    float m3 = (lane == i1 || lane == i2) ? -1e30f : a;
#pragma unroll
    for (int o = 32; o; o >>= 1) m3 = fmaxf(m3, __shfl_xor(m3, o, 64));
    const float p = expf(a - m1);
    const float ssum = wsum(p);
    const float prob = p / ssum;
    psum_local += prob;
    const float s1 = rlf(prob, i1);
    const float s2 = rlf(prob, i2);
    if (lane == 0) {
      const float inv = 1.f / (s1 + s2);
      o_ts[tok * 2 + 0] = s1 * inv;
      o_ts[tok * 2 + 1] = s2 * inv;
      o_ti[tok * 2 + 0] = (float)i1;
      o_ti[tok * 2 + 1] = (float)i2;
      atomicAdd(&scnt[i1], 1.f);
      atomicAdd(&scnt[i2], 1.f);
      if (m1 - m2 < TAU || m2 - m3 < TAU) {
        int slot = atomicAdd(qd, 1);
        qd[8 + slot] = tok;
      }
    }
  }
  atomicAdd(&sP[lane], psum_local);
  if (lane == 0) atomicAdd(&scomp, comp_local);
  __syncthreads();
  if (tid < 64) {
    atomicAdd(&ws[64 + tid], sP[tid]);
    atomicAdd(&ws[128 + tid], scnt[tid]);
  }
  if (tid == 0) atomicAdd(&ws[192], scomp);
}

// ---------------- K4: exact fp32 repair of margin-flagged tokens ---------------
__global__ __launch_bounds__(256) void repair_kernel(
    const float* __restrict__ x, const float* __restrict__ gate_w,
    const float* __restrict__ eb_p, float* __restrict__ ws,
    float* __restrict__ out, int N)
{
  const int tid = threadIdx.x;
  __shared__ float red[256];
  int* qd = (int*)(ws + 200);
  const int qn = qd[0];
  float* o_ts = out;
  float* o_ti = out + 2 * N;

  for (int e = blockIdx.x; e < qn; e += gridDim.x) {
    const int tok = qd[8 + e];
    const int o = tid & 63;
    const int kq = tid >> 6;
    const float* xr = x + (size_t)tok * 4096 + kq * 1024;
    const float* wr = gate_w + (size_t)o * 4096 + kq * 1024;
    float s = 0.f;
#pragma unroll 4
    for (int j = 0; j < 256; ++j) {
      const float4 xv = *(const float4*)(xr + j * 4);
      const float4 wv = *(const float4*)(wr + j * 4);
      s = fmaf(xv.x, wv.x, s); s = fmaf(xv.y, wv.y, s);
      s = fmaf(xv.z, wv.z, s); s = fmaf(xv.w, wv.w, s);
    }
    red[tid] = s;
    __syncthreads();
    if (tid < 64) {
      const float a = red[tid] + red[64 + tid] + red[128 + tid] +
                      red[192 + tid] + eb_p[tid] - ws[tid];
      const int lane = tid;
      float m1 = a; int i1 = lane;
#pragma unroll
      for (int oo = 32; oo; oo >>= 1) {
        const float ov = __shfl_xor(m1, oo, 64);
        const int oi = __shfl_xor(i1, oo, 64);
        if (ov > m1 || (ov == m1 && oi < i1)) { m1 = ov; i1 = oi; }
      }
      float m2 = (lane == i1) ? -1e30f : a; int i2 = lane;
#pragma unroll
      for (int oo = 32; oo; oo >>= 1) {
        const float ov = __shfl_xor(m2, oo, 64);
        const int oi = __shfl_xor(i2, oo, 64);
        if (ov > m2 || (ov == m2 && oi < i2)) { m2 = ov; i2 = oi; }
      }
      const float p = expf(a - m1);
      const float ssum = wsum(p);
      const float s1 = rlf(p, i1) / ssum;
      const float s2 = rlf(p, i2) / ssum;
      if (lane == 0) {
        const int i1o = (int)o_ti[tok * 2 + 0];
        const int i2o = (int)o_ti[tok * 2 + 1];
        const float inv = 1.f / (s1 + s2);
        o_ts[tok * 2 + 0] = s1 * inv;
        o_ts[tok * 2 + 1] = s2 * inv;
        o_ti[tok * 2 + 0] = (float)i1;
        o_ti[tok * 2 + 1] = (float)i2;
        if (i1o != i1 || i2o != i2) {
          atomicAdd(&ws[128 + i1o], -1.f);
          atomicAdd(&ws[128 + i2o], -1.f);
          atomicAdd(&ws[128 + i1], 1.f);
          atomicAdd(&ws[128 + i2], 1.f);
        }
      }
    }
    __syncthreads();
  }
}

// ---------------- K5: finalize aux_loss + capacity ----------------
__global__ __launch_bounds__(64) void fin_kernel(const float* __restrict__ ws,
                                                 float* __restrict__ out, int N) {
  const int e = threadIdx.x;
  const float P = ws[64 + e] / (float)N;
  const float f = ws[128 + e] / (float)(2 * N);
  const float v = wsum(f * P);
  if (e == 0) {
    out[4 * N + 0] = 64.f * v;
    float cap = 0.5f + 1.5f * (ws[192] / (float)N);
    out[4 * N + 1] = fminf(fmaxf(cap, 0.5f), 2.f);
  }
}

extern "C" void kernel_launch(void* const* d_in, const int* in_sizes, int n_in,
                              void* d_out, int out_size, void* d_ws, size_t ws_size,
                              hipStream_t stream) {
  const float* x          = (const float*)d_in[0];
  const float* gate_w     = (const float*)d_in[1];
  const float* expert_bias= (const float*)d_in[2];
  const float* cp_w1      = (const float*)d_in[3];
  const float* cp_b1      = (const float*)d_in[4];
  const float* cp_w2      = (const float*)d_in[5];
  const float* cp_b2      = (const float*)d_in[6];
  const float* load_buffer= (const float*)d_in[7];
  const float* wih0       = (const float*)d_in[8];
  const float* whh0       = (const float*)d_in[9];
  const float* bih0       = (const float*)d_in[10];
  const float* bhh0       = (const float*)d_in[11];
  const float* wih1       = (const float*)d_in[12];
  const float* whh1       = (const float*)d_in[13];
  const float* bih1       = (const float*)d_in[14];
  const float* bhh1       = (const float*)d_in[15];
  const float* head_w     = (const float*)d_in[16];
  const float* head_b     = (const float*)d_in[17];
  float* out = (float*)d_out;
  float* ws  = (float*)d_ws;
  const int N = in_sizes[0] / 4096;  // 16384 tokens

  prep_kernel<<<128, 256, 0, stream>>>(gate_w, cp_w1, ws);
  gemm_kernel<<<1025, 256, 0, stream>>>(x, ws, out, load_buffer,
                                        wih0, whh0, bih0, bhh0,
                                        wih1, whh1, bih1, bhh1,
                                        head_w, head_b, N);
  epi_kernel<<<N / 32, 256, 0, stream>>>(expert_bias, cp_b1, cp_w2, cp_b2,
                                         ws, out, N);
  repair_kernel<<<128, 256, 0, stream>>>(x, gate_w, expert_bias, ws, out, N);
  fin_kernel<<<1, 64, 0, stream>>>(ws, out, N);
}